// Round 5
// baseline (1005.430 us; speedup 1.0000x reference)
//
#include <hip/hip_runtime.h>
#include <hip/hip_bf16.h>
#include <stdint.h>

// Problem constants (compile-time; shapes fixed by setup_inputs()).
#define M_ROWS 4096      // batch rows of x
#define IN_F   4096      // K
#define OUT_F  11008     // N
#define N_GROUPS 32      // IN_F / 128
#define ALPHA  0.05f

typedef __bf16 bf16;
typedef __bf16 bf16x8 __attribute__((ext_vector_type(8)));
typedef float  floatx4 __attribute__((ext_vector_type(4)));

// async global->LDS, 16B per lane; LDS dest = wave-uniform base + lane*16
__device__ __forceinline__ void async_copy16(const void* g, void* l) {
  __builtin_amdgcn_global_load_lds(
      (const __attribute__((address_space(1))) void*)g,
      (__attribute__((address_space(3))) void*)l, 16, 0, 0);
}

// ---------------------------------------------------------------------------
// Phase 1 (fused): grid-strided, 2048 blocks. Streaming floor ~110 us.
// Round-2 evidence: residual (total - gemm) identical between split one-shot
// and fused grid-stride versions -> prep is at/near its BW floor; remaining
// residual is harness reset overhead. Unchanged.
// ---------------------------------------------------------------------------
__global__ __launch_bounds__(256) void prep_kernel(
    const float* __restrict__ x, const int* __restrict__ q,
    const float* __restrict__ scales, const float* __restrict__ zeros,
    const float* __restrict__ noise, bf16* __restrict__ wn,
    bf16* __restrict__ xb) {
  const int W_CH = OUT_F * (IN_F >> 3);              // 5,636,096 weight chunks
  const int T_CH = W_CH + (M_ROWS * (IN_F >> 3));    // + 2,097,152 x chunks
  const int stride = gridDim.x * 256;
  for (int idx = blockIdx.x * 256 + threadIdx.x; idx < T_CH; idx += stride) {
    if (idx < W_CH) {
      int o = idx >> 9;                  // 512 chunks per output row
      int i = (idx & 511) << 3;          // 8-aligned -> single group
      int g = i >> 7;
      float s = scales[o * N_GROUPS + g];
      float z = zeros[o * N_GROUPS + g];
      size_t base = (size_t)o * IN_F + i;
      int4   q0 = *(const int4*)(q + base);
      int4   q1 = *(const int4*)(q + base + 4);
      float4 n0 = *(const float4*)(noise + base);
      float4 n1 = *(const float4*)(noise + base + 4);
      float qs[8] = {(float)q0.x, (float)q0.y, (float)q0.z, (float)q0.w,
                     (float)q1.x, (float)q1.y, (float)q1.z, (float)q1.w};
      float ns[8] = {n0.x, n0.y, n0.z, n0.w, n1.x, n1.y, n1.z, n1.w};
      bf16x8 outv;
#pragma unroll
      for (int j = 0; j < 8; ++j) {
        float w = (qs[j] - z) * s;
        float v = fmaf(ALPHA * fabsf(w), ns[j], w);   // w + noise*ALPHA*|w|
        outv[j] = (bf16)v;
      }
      *(bf16x8*)(wn + base) = outv;
    } else {
      size_t base = (size_t)(idx - W_CH) << 3;
      float4 a0 = *(const float4*)(x + base);
      float4 a1 = *(const float4*)(x + base + 4);
      float vs[8] = {a0.x, a0.y, a0.z, a0.w, a1.x, a1.y, a1.z, a1.w};
      bf16x8 outv;
#pragma unroll
      for (int j = 0; j < 8; ++j) outv[j] = (bf16)vs[j];
      *(bf16x8*)(xb + base) = outv;
    }
  }
}

// ---------------------------------------------------------------------------
// Phase 2: 256x256-tile GEMM; A via LDS ring, B DIRECT-TO-REGISTER (round 5).
//
// ROUND-4 ARITHMETIC: steady pair time ~2160 cyc/CU vs floors MFMA 1242 /
// LDS 1150-1450 -> LDS traffic (96KB rd + 32KB wr per pair) co-bottlenecks.
// B fragments are wave-private (16B/lane, rows nbase+wc*64+ni*16+frow), so
// B skips LDS: loaded global->VGPR one pair ahead, double-buffered bqA/bqB.
// LDS per pair drops to A only (64KB rd + 16KB wr ~= 640-940 cyc < 1242);
// LDS size 128->64 KiB; first MFMA waits on 1 ds_read + in-reg B.
//
// SYNCHRONIZATION (simpler than round 4):
//  - A-ring unchanged: 4 slots x 16KB, stage slot j+3 during pair j (WAR
//    safe: slot j+3's last reader finished before barrier j-1, which every
//    wave passed before issuing pair-j stages; write's next reader is pair
//    j+3, after the landing proof).
//  - Landing proof is now IMPLICIT: compiler MUST emit a vmcnt wait before
//    pair j's MFMAs for the bq(j) registers (loaded in pair j-1). FIFO
//    vmcnt retirement => that wait also retires everything older, including
//    A(j+1) (issued pair j-2 < pair j-1). Per-pair sched_barrier(0) fences
//    pin all vmem issues inside their pair, so cross-pair issue order is
//    guaranteed. The barrier then propagates wave-local proofs block-wide.
//    => NO manual vmcnt in the main loop at all; raw s_barrier only.
//  - Prologue: issue B(0), stage A(0..2); queue [B0(4),A0(2),A1(2),A2(2)];
//    vmcnt(4) retires B0+A0; barrier.
//
// LDS layout/swizzle for A (round-1, measured conflict-free): logical
// (row r, 8-elem chunk kc) at elem (r>>1)*64 + pc*8,
// pc = (((r&1)<<2)|kc) ^ ((r>>1)&7); staging realizes it by pre-permuting
// each lane's GLOBAL source chunk (LDS dest linear per gload_lds rules).
// B global loads: per-lane 16B at W + (n-row)*IN_F + kh*32 + g4*8 ->
// 16 distinct 64B-aligned segments per instr (4 g4-lanes contiguous); no
// overfetch; L2-resident panel (2MB/block).
// ---------------------------------------------------------------------------
__global__ __launch_bounds__(512, 2) void gemm_bd_kernel(
    const bf16* __restrict__ A,    // [M_ROWS][IN_F]
    const bf16* __restrict__ W,    // [OUT_F][IN_F]
    const float* __restrict__ bias,
    float* __restrict__ C) {       // [M_ROWS][OUT_F]
  __shared__ bf16 lds[4 * 8192];   // 4 A-slots x 256 rows x 32 k

  const int tid = threadIdx.x;
  const int wv = tid >> 6;          // wave 0..7
  const int ln = tid & 63;
  const int wr = wv >> 2;           // wave M row (0..1) -> rows wr*128..+128
  const int wc = wv & 3;            // wave N col (0..3) -> cols wc*64..+64

  // XCD-bijective swizzle (688 = 8*86) + m-pair supertile: each XCD sweeps
  // bn with 2 resident A panels; B tile (2MB) L2-resident per XCD.
  const int orig = blockIdx.x;
  const int idx  = orig >> 3;                    // 0..85
  const int bm   = ((orig & 7) << 1) | (idx & 1);
  const int bn   = idx >> 1;
  const int mbase = bm << 8;
  const int nbase = bn << 8;

  // A staging source (per-lane pre-swizzled global address; LDS dest linear).
  const int dec    = (ln & 7) ^ (ln >> 3);
  const int rstage = wv * 32 + (ln >> 3) * 2 + (dec >> 2);  // j=0 row; j=1 +16
  const int kcol   = (dec & 3) * 8;
  const bf16* aS = A + (size_t)(mbase + rstage) * IN_F + kcol;

  // A fragment ds_read offsets (elements); mi*512 advances 16 rows.
  const int frow = ln & 15;
  const int g4   = ln >> 4;
  const int pc   = (((frow & 1) << 2) | g4) ^ (frow >> 1);
  const int aoff = (wr * 64 + (frow >> 1)) * 64 + pc * 8;

  // B fragment global pointers (wave-private; fragment ni, pair kh at
  // bP[ni] + kh*32 elems). Static unrolled indexing only (rule #20).
  const bf16* bP[4];
#pragma unroll
  for (int ni = 0; ni < 4; ++ni)
    bP[ni] = W + (size_t)(nbase + wc * 64 + ni * 16 + frow) * IN_F + g4 * 8;

  floatx4 acc[8][4] = {};
  bf16x8 bqA[4], bqB[4];

#define STAGE_A(DST, KH)                                                          \
  do {                                                                            \
    async_copy16(aS + (size_t)(KH) * 32,             &lds[(DST) * 8192 + wv * 1024]);        \
    async_copy16(aS + (size_t)(KH) * 32 + 16 * IN_F, &lds[(DST) * 8192 + wv * 1024 + 512]);  \
  } while (0)

  // Prologue: B(0) then A-stage P0..P2; vmcnt(4) proves B0+A0; barrier.
#pragma unroll
  for (int ni = 0; ni < 4; ++ni) bqA[ni] = *(const bf16x8*)(bP[ni]);
  STAGE_A(0, 0);
  STAGE_A(1, 1);
  STAGE_A(2, 2);
  asm volatile("s_waitcnt vmcnt(4)" ::: "memory");
  __builtin_amdgcn_s_barrier();
  __builtin_amdgcn_sched_barrier(0);

  // One pair = K=32: 8 ds_read_b128 (A) + 4 B-loads (next pair) +
  // 2 gload_lds (A-stage, 3 ahead) + 32 MFMA + raw barrier. No manual vmcnt.
#define PAIR(SLOT, KH, BQC, BQN, DO_B, DO_STAGE)                                  \
  {                                                                               \
    bf16x8 afr[8];                                                                \
    _Pragma("unroll") for (int mi = 0; mi < 8; ++mi)                              \
      afr[mi] = *(const bf16x8*)&lds[(SLOT) * 8192 + aoff + mi * 512];            \
    if (DO_B) {                                                                   \
      _Pragma("unroll") for (int ni = 0; ni < 4; ++ni)                            \
        BQN[ni] = *(const bf16x8*)(bP[ni] + ((KH) + 1) * 32);                     \
    }                                                                             \
    if (DO_STAGE) STAGE_A(((SLOT) + 3) & 3, (KH) + 3);                            \
    __builtin_amdgcn_s_setprio(1);                                                \
    _Pragma("unroll") for (int mi = 0; mi < 8; ++mi)                              \
      _Pragma("unroll") for (int ni = 0; ni < 4; ++ni)                            \
        acc[mi][ni] = __builtin_amdgcn_mfma_f32_16x16x32_bf16(                    \
            afr[mi], BQC[ni], acc[mi][ni], 0, 0, 0);                              \
    __builtin_amdgcn_s_setprio(0);                                                \
    __builtin_amdgcn_s_barrier();                                                 \
    __builtin_amdgcn_sched_barrier(0);                                            \
  }

  // Main loop: pairs 0..123 (B ping-pong parity even per 4-pair iter).
  for (int kh = 0; kh < 124; kh += 4) {
    PAIR(0, kh + 0, bqA, bqB, true, true);
    PAIR(1, kh + 1, bqB, bqA, true, true);
    PAIR(2, kh + 2, bqA, bqB, true, true);
    PAIR(3, kh + 3, bqB, bqA, true, true);
  }
  // Tail: pair 124 stages A(127); B loads stop after pair 126 (loads B127).
  PAIR(0, 124, bqA, bqB, true, true);
  PAIR(1, 125, bqB, bqA, true, false);
  PAIR(2, 126, bqA, bqB, true, false);
  PAIR(3, 127, bqB, bqA, false, false);

#undef PAIR
#undef STAGE_A

  // Epilogue. C/D layout (m89-verified): col = lane&15, row = (lane>>4)*4 + reg.
#pragma unroll
  for (int ni = 0; ni < 4; ++ni) {
    int n = nbase + wc * 64 + ni * 16 + (ln & 15);
    float bv = bias[n];
#pragma unroll
    for (int mi = 0; mi < 8; ++mi) {
      int m0 = mbase + wr * 128 + mi * 16 + (ln >> 4) * 4;
#pragma unroll
      for (int r = 0; r < 4; ++r)
        C[(size_t)(m0 + r) * OUT_F + n] = acc[mi][ni][r] + bv;
    }
  }
}

// ---------------------------------------------------------------------------
extern "C" void kernel_launch(void* const* d_in, const int* in_sizes, int n_in,
                              void* d_out, int out_size, void* d_ws, size_t ws_size,
                              hipStream_t stream) {
  const float* x       = (const float*)d_in[0];  // [4096][4096]
  const int*   qweight = (const int*)d_in[1];    // [11008][4096]
  const float* scales  = (const float*)d_in[2];  // [11008][32]
  const float* zeros   = (const float*)d_in[3];  // [11008][32]
  const float* bias    = (const float*)d_in[4];  // [11008]
  const float* noise   = (const float*)d_in[5];  // [11008][4096]
  float* out = (float*)d_out;                    // [4096][11008]

  // Workspace layout: wn bf16 [OUT_F][IN_F] (90.2 MB), then xb bf16 (33.6 MB).
  bf16* wn = (bf16*)d_ws;
  bf16* xb = (bf16*)((char*)d_ws + (size_t)OUT_F * IN_F * sizeof(bf16));

  // Phase 1: fused dequant+noise+xcast, grid-strided at 8 blocks/CU.
  prep_kernel<<<2048, 256, 0, stream>>>(x, qweight, scales, zeros, noise, wn, xb);

  // Phase 2: 256x256-tile bf16 MFMA GEMM (A-LDS ring + B-direct-to-reg).
  // Grid: (11008/256)*(4096/256) = 43*16 = 688 = 8 XCDs * 86.
  gemm_bd_kernel<<<dim3(688), 512, 0, stream>>>(xb, wn, bias, out);
}